// Round 1
// baseline (18110.817 us; speedup 1.0000x reference)
//
#include <hip/hip_runtime.h>
#include <math.h>

#define BTOT 256
#define T 1024
#define DIN 64
#define H 128
#define G4 512   // 4*H

__device__ __forceinline__ float sigmoidf_(float x) { return 1.0f / (1.0f + expf(-x)); }

// ---------------------------------------------------------------------------
// Layer 0 scan with fused input transform.
// grid = nb blocks (one batch element each), 512 threads (one gate each).
// Thread j holds w_ih0[j,0:64] and w_hh0[j,0:128] in registers (192 VGPRs).
// h broadcast via LDS; c lives in registers of threads j<128.
// ---------------------------------------------------------------------------
__global__ __launch_bounds__(512)
void scan_l0(const float* __restrict__ x, const float* __restrict__ h0in,
             const float* __restrict__ wih, const float* __restrict__ whh,
             const float* __restrict__ bias, float* __restrict__ h0out,
             int bstart)
{
    __shared__ __align__(16) float lds_x[DIN];
    __shared__ __align__(16) float lds_h[H];
    __shared__ __align__(16) float lds_g[G4];

    const int j  = threadIdx.x;
    const int bg = bstart + blockIdx.x;        // global batch index
    const int bl = blockIdx.x;                 // chunk-local batch index

    // register-resident weights
    float wi[DIN];
    float wh[H];
    {
        const float4* p = (const float4*)(wih + (size_t)j * DIN);
        #pragma unroll
        for (int q = 0; q < DIN / 4; ++q) {
            float4 v = p[q];
            wi[4*q+0] = v.x; wi[4*q+1] = v.y; wi[4*q+2] = v.z; wi[4*q+3] = v.w;
        }
        const float4* ph = (const float4*)(whh + (size_t)j * H);
        #pragma unroll
        for (int q = 0; q < H / 4; ++q) {
            float4 v = ph[q];
            wh[4*q+0] = v.x; wh[4*q+1] = v.y; wh[4*q+2] = v.z; wh[4*q+3] = v.w;
        }
    }
    const float bj = bias[j];

    // init h (layer 0 row of h0in [L,B,H]) and c=0
    if (j < H) lds_h[j] = h0in[(size_t)0 * BTOT * H + (size_t)bg * H + j];
    float c = 0.0f;

    // prefetch x_t for t=0
    float xpre = 0.0f;
    if (j < DIN) xpre = x[((size_t)bg * T + 0) * DIN + j];

    for (int t = 0; t < T; ++t) {
        if (j < DIN) lds_x[j] = xpre;
        __syncthreads();   // x_t and h_t visible to all
        if (j < DIN) {
            int tn = (t + 1 < T) ? (t + 1) : t;
            xpre = x[((size_t)bg * T + tn) * DIN + j];   // prefetch next step
        }

        // gate j pre-activation: 4 independent FMA chains
        float a0 = 0.f, a1 = 0.f, a2 = 0.f, a3 = 0.f;
        const float4* lx = (const float4*)lds_x;
        #pragma unroll
        for (int q = 0; q < DIN / 4; ++q) {
            float4 v = lx[q];
            a0 += wi[4*q+0] * v.x; a1 += wi[4*q+1] * v.y;
            a2 += wi[4*q+2] * v.z; a3 += wi[4*q+3] * v.w;
        }
        const float4* lh = (const float4*)lds_h;
        #pragma unroll
        for (int q = 0; q < H / 4; ++q) {
            float4 v = lh[q];
            a0 += wh[4*q+0] * v.x; a1 += wh[4*q+1] * v.y;
            a2 += wh[4*q+2] * v.z; a3 += wh[4*q+3] * v.w;
        }
        lds_g[j] = bj + ((a0 + a1) + (a2 + a3));
        __syncthreads();   // gates visible

        if (j < H) {
            float gi = lds_g[j], gf = lds_g[H + j], gg = lds_g[2*H + j], go = lds_g[3*H + j];
            c = sigmoidf_(gf) * c + sigmoidf_(gi) * tanhf(gg);
            float h = sigmoidf_(go) * tanhf(c);
            lds_h[j] = h;
            h0out[((size_t)bl * T + t) * H + j] = h;
        }
        // next iteration's first __syncthreads() orders lds_h writes vs reads
    }
}

// ---------------------------------------------------------------------------
// xg1 = h0_seq @ w_ih1^T + b1.  A = [nb*T, 128], W = [512,128], Out = [nb*T, 512].
// grid = nb*16 blocks (64 A-rows each), 512 threads (one output column each).
// W row register-resident; A tile broadcast from LDS.
// ---------------------------------------------------------------------------
__global__ __launch_bounds__(512)
void xg_gemm(const float* __restrict__ A, const float* __restrict__ W,
             const float* __restrict__ bias, float* __restrict__ Out)
{
    __shared__ __align__(16) float As[64][H];   // 32 KB

    const int j = threadIdx.x;
    const size_t m0 = (size_t)blockIdx.x * 64;

    float w[H];
    {
        const float4* p = (const float4*)(W + (size_t)j * H);
        #pragma unroll
        for (int q = 0; q < H / 4; ++q) {
            float4 v = p[q];
            w[4*q+0] = v.x; w[4*q+1] = v.y; w[4*q+2] = v.z; w[4*q+3] = v.w;
        }
    }
    const float bj = bias[j];

    // stage A tile: 64*128 floats = 2048 float4, 512 threads -> 4 each (coalesced)
    {
        const float4* A4 = (const float4*)(A + m0 * H);
        float4* As4 = (float4*)&As[0][0];
        #pragma unroll
        for (int i = 0; i < 4; ++i) As4[j + i * 512] = A4[j + i * 512];
    }
    __syncthreads();

    for (int m = 0; m < 64; ++m) {
        float a0 = 0.f, a1 = 0.f, a2 = 0.f, a3 = 0.f;
        const float4* ar = (const float4*)&As[m][0];
        #pragma unroll
        for (int q = 0; q < H / 4; ++q) {
            float4 v = ar[q];
            a0 += w[4*q+0] * v.x; a1 += w[4*q+1] * v.y;
            a2 += w[4*q+2] * v.z; a3 += w[4*q+3] * v.w;
        }
        Out[(m0 + m) * G4 + j] = bj + ((a0 + a1) + (a2 + a3));
    }
}

// ---------------------------------------------------------------------------
// Layer 1 scan (input transform precomputed in xg1), fused final FC.
// grid = nb blocks, 512 threads. Thread j holds w_hh1[j,:] (128 VGPRs).
// xg1[b,t,j] prefetched per-thread (coalesced 2KB/WG/step).
// ---------------------------------------------------------------------------
__global__ __launch_bounds__(512)
void scan_l1(const float* __restrict__ xg1, const float* __restrict__ h0in,
             const float* __restrict__ whh, const float* __restrict__ fcw,
             const float* __restrict__ fcb, float* __restrict__ out,
             int bstart)
{
    __shared__ __align__(16) float lds_h[H];
    __shared__ __align__(16) float lds_g[G4];

    const int j  = threadIdx.x;
    const int bg = bstart + blockIdx.x;
    const int bl = blockIdx.x;

    float wh[H];
    {
        const float4* p = (const float4*)(whh + (size_t)j * H);
        #pragma unroll
        for (int q = 0; q < H / 4; ++q) {
            float4 v = p[q];
            wh[4*q+0] = v.x; wh[4*q+1] = v.y; wh[4*q+2] = v.z; wh[4*q+3] = v.w;
        }
    }

    if (j < H) lds_h[j] = h0in[(size_t)1 * BTOT * H + (size_t)bg * H + j];
    float c = 0.0f;

    float xg_next = xg1[((size_t)bl * T + 0) * G4 + j];
    __syncthreads();   // lds_h init visible

    for (int t = 0; t < T; ++t) {
        float g = xg_next;
        if (t + 1 < T) xg_next = xg1[((size_t)bl * T + (t + 1)) * G4 + j];

        float a0 = 0.f, a1 = 0.f, a2 = 0.f, a3 = 0.f;
        const float4* lh = (const float4*)lds_h;
        #pragma unroll
        for (int q = 0; q < H / 4; ++q) {
            float4 v = lh[q];
            a0 += wh[4*q+0] * v.x; a1 += wh[4*q+1] * v.y;
            a2 += wh[4*q+2] * v.z; a3 += wh[4*q+3] * v.w;
        }
        lds_g[j] = g + ((a0 + a1) + (a2 + a3));
        __syncthreads();

        if (j < H) {
            float gi = lds_g[j], gf = lds_g[H + j], gg = lds_g[2*H + j], go = lds_g[3*H + j];
            c = sigmoidf_(gf) * c + sigmoidf_(gi) * tanhf(gg);
            lds_h[j] = sigmoidf_(go) * tanhf(c);
        }
        __syncthreads();   // h_{t+1} visible before next dot
    }

    // final FC on h_T: out[bg] = dot(h, fc_w) + fc_b
    if (j < H) lds_g[j] = lds_h[j] * fcw[j];
    __syncthreads();
    if (j == 0) {
        float s = fcb[0];
        for (int k = 0; k < H; ++k) s += lds_g[k];
        out[bg] = s;
    }
}

extern "C" void kernel_launch(void* const* d_in, const int* in_sizes, int n_in,
                              void* d_out, int out_size, void* d_ws, size_t ws_size,
                              hipStream_t stream)
{
    const float* x    = (const float*)d_in[0];
    const float* h0   = (const float*)d_in[1];
    const float* wih0 = (const float*)d_in[2];
    const float* whh0 = (const float*)d_in[3];
    const float* b0   = (const float*)d_in[4];
    const float* wih1 = (const float*)d_in[5];
    const float* whh1 = (const float*)d_in[6];
    const float* b1   = (const float*)d_in[7];
    const float* fcw  = (const float*)d_in[8];
    const float* fcb  = (const float*)d_in[9];
    float* out = (float*)d_out;

    // workspace: h0 sequence [nb,T,H] + xg1 [nb,T,4H], fp32. Chunk batch if needed.
    const size_t per_b = (size_t)T * (H + G4) * sizeof(float);   // 2.625 MB
    int chunkB = BTOT;
    while (chunkB > 1 && (size_t)chunkB * per_b > ws_size) chunkB >>= 1;

    float* h0_ws  = (float*)d_ws;
    float* xg1_ws = h0_ws + (size_t)chunkB * T * H;

    for (int bs = 0; bs < BTOT; bs += chunkB) {
        int nb = (BTOT - bs < chunkB) ? (BTOT - bs) : chunkB;
        scan_l0<<<nb, 512, 0, stream>>>(x, h0, wih0, whh0, b0, h0_ws, bs);
        xg_gemm<<<nb * (T / 64), 512, 0, stream>>>(h0_ws, wih1, b1, xg1_ws);
        scan_l1<<<nb, 512, 0, stream>>>(xg1_ws, h0, whh1, fcw, fcb, out, bs);
    }
}

// Round 2
// 3765.390 us; speedup vs baseline: 4.8098x; 4.8098x over previous
//
#include <hip/hip_runtime.h>
#include <math.h>

#define NB   256
#define T    1024
#define DIN  64
#define H    128
#define G4   512   // 4*H

// wave-uniform broadcast: value from lane l of this wave -> SGPR
__device__ __forceinline__ float bcast(float v, int l) {
    return __int_as_float(__builtin_amdgcn_readlane(__float_as_int(v), l));
}
__device__ __forceinline__ float sigf(float x)   { return 1.0f / (1.0f + __expf(-x)); }
__device__ __forceinline__ float tanhf_(float x) { return 2.0f / (1.0f + __expf(-2.0f * x)) - 1.0f; }

// ---------------------------------------------------------------------------
// Layer-0 scan over a time tile [t0, t0+ntile). grid=256 (one batch each),
// 512 threads (one gate each). Weights register-resident (wi 64 + wh 128).
// h broadcast via v_readlane from lane-distributed registers; LDS only to
// exchange h/gates across waves (2 barriers/step).
// ---------------------------------------------------------------------------
__global__ __launch_bounds__(512, 2)
void scan_l0_tile(const float* __restrict__ x, const float* __restrict__ h0in,
                  const float* __restrict__ wih, const float* __restrict__ whh,
                  const float* __restrict__ bias, float* __restrict__ h0_tile,
                  float* __restrict__ st_h, float* __restrict__ st_c,
                  int t0, int ntile)
{
    __shared__ __align__(16) float lds_h[H];
    __shared__ __align__(16) float lds_g[G4];

    const int j    = threadIdx.x;
    const int b    = blockIdx.x;
    const int lane = j & 63;

    float wi[DIN];
    float wh[H];
    {
        const float4* p = (const float4*)(wih + (size_t)j * DIN);
        #pragma unroll
        for (int q = 0; q < DIN / 4; ++q) {
            float4 v = p[q];
            wi[4*q] = v.x; wi[4*q+1] = v.y; wi[4*q+2] = v.z; wi[4*q+3] = v.w;
        }
        const float4* ph = (const float4*)(whh + (size_t)j * H);
        #pragma unroll
        for (int q = 0; q < H / 4; ++q) {
            float4 v = ph[q];
            wh[4*q] = v.x; wh[4*q+1] = v.y; wh[4*q+2] = v.z; wh[4*q+3] = v.w;
        }
    }
    const float bj = bias[j];

    float c = 0.0f;
    if (j < H) {
        lds_h[j] = (t0 == 0) ? h0in[(size_t)b * H + j] : st_h[(size_t)b * H + j];
        c        = (t0 == 0) ? 0.0f                    : st_c[(size_t)b * H + j];
    }
    __syncthreads();

    // x prefetch (wave-redundant load, L1-served)
    float xv_next = x[((size_t)b * T + t0) * DIN + lane];

    for (int tt = 0; tt < ntile; ++tt) {
        const float hv0 = lds_h[lane];
        const float hv1 = lds_h[64 + lane];
        const float xv  = xv_next;
        {
            int tn = (tt + 1 < ntile) ? (t0 + tt + 1) : (t0 + tt);
            xv_next = x[((size_t)b * T + tn) * DIN + lane];
        }

        float a0 = 0.f, a1 = 0.f, a2 = 0.f, a3 = 0.f;
        #pragma unroll
        for (int k = 0; k < DIN; k += 4) {
            a0 += wi[k]   * bcast(xv, k);
            a1 += wi[k+1] * bcast(xv, k+1);
            a2 += wi[k+2] * bcast(xv, k+2);
            a3 += wi[k+3] * bcast(xv, k+3);
        }
        #pragma unroll
        for (int k = 0; k < 64; k += 4) {
            a0 += wh[k]   * bcast(hv0, k);
            a1 += wh[k+1] * bcast(hv0, k+1);
            a2 += wh[k+2] * bcast(hv0, k+2);
            a3 += wh[k+3] * bcast(hv0, k+3);
        }
        #pragma unroll
        for (int k = 0; k < 64; k += 4) {
            a0 += wh[64+k]   * bcast(hv1, k);
            a1 += wh[64+k+1] * bcast(hv1, k+1);
            a2 += wh[64+k+2] * bcast(hv1, k+2);
            a3 += wh[64+k+3] * bcast(hv1, k+3);
        }
        lds_g[j] = bj + ((a0 + a1) + (a2 + a3));
        __syncthreads();

        if (j < H) {
            float gi = lds_g[j], gf = lds_g[H + j], gg = lds_g[2*H + j], go = lds_g[3*H + j];
            c = sigf(gf) * c + sigf(gi) * tanhf_(gg);
            float h = sigf(go) * tanhf_(c);
            lds_h[j] = h;
            h0_tile[((size_t)b * ntile + tt) * H + j] = h;
        }
        __syncthreads();
    }

    if (j < H) {
        st_h[(size_t)b * H + j] = lds_h[j];
        st_c[(size_t)b * H + j] = c;
    }
}

// ---------------------------------------------------------------------------
// xg1 tile GEMM: Out[r,j] = sum_k A[r,k]*W[j,k] + b[j], A=[NB*ntile,128].
// grid = NB*ntile/64 blocks, 512 threads (one output column each).
// A rows lane-distributed + readlane broadcast; prefetched.
// ---------------------------------------------------------------------------
__global__ __launch_bounds__(512, 2)
void xg1_tile(const float* __restrict__ A, const float* __restrict__ W,
              const float* __restrict__ bias, float* __restrict__ Out)
{
    const int j    = threadIdx.x;
    const int lane = j & 63;
    const size_t m0 = (size_t)blockIdx.x * 64;

    float w[H];
    {
        const float4* p = (const float4*)(W + (size_t)j * H);
        #pragma unroll
        for (int q = 0; q < H / 4; ++q) {
            float4 v = p[q];
            w[4*q] = v.x; w[4*q+1] = v.y; w[4*q+2] = v.z; w[4*q+3] = v.w;
        }
    }
    const float bj = bias[j];

    const float* Ab = A + m0 * H;
    float n0 = Ab[lane], n1 = Ab[64 + lane];

    for (int m = 0; m < 64; ++m) {
        const float av0 = n0, av1 = n1;
        if (m + 1 < 64) {
            n0 = Ab[(m + 1) * H + lane];
            n1 = Ab[(m + 1) * H + 64 + lane];
        }
        float a0 = 0.f, a1 = 0.f, a2 = 0.f, a3 = 0.f;
        #pragma unroll
        for (int k = 0; k < 64; k += 4) {
            a0 += w[k]   * bcast(av0, k);
            a1 += w[k+1] * bcast(av0, k+1);
            a2 += w[k+2] * bcast(av0, k+2);
            a3 += w[k+3] * bcast(av0, k+3);
        }
        #pragma unroll
        for (int k = 0; k < 64; k += 4) {
            a0 += w[64+k]   * bcast(av1, k);
            a1 += w[64+k+1] * bcast(av1, k+1);
            a2 += w[64+k+2] * bcast(av1, k+2);
            a3 += w[64+k+3] * bcast(av1, k+3);
        }
        Out[(m0 + m) * G4 + j] = bj + ((a0 + a1) + (a2 + a3));
    }
}

// ---------------------------------------------------------------------------
// Layer-1 scan over a time tile; xg precomputed (bias included). Fused FC on
// the last step of the last tile.
// ---------------------------------------------------------------------------
__global__ __launch_bounds__(512, 2)
void scan_l1_tile(const float* __restrict__ xg, const float* __restrict__ h0in,
                  const float* __restrict__ whh, const float* __restrict__ fcw,
                  const float* __restrict__ fcb, float* __restrict__ out,
                  float* __restrict__ st_h, float* __restrict__ st_c,
                  int t0, int ntile)
{
    __shared__ __align__(16) float lds_h[H];
    __shared__ __align__(16) float lds_g[G4];

    const int j    = threadIdx.x;
    const int b    = blockIdx.x;
    const int lane = j & 63;

    float wh[H];
    {
        const float4* p = (const float4*)(whh + (size_t)j * H);
        #pragma unroll
        for (int q = 0; q < H / 4; ++q) {
            float4 v = p[q];
            wh[4*q] = v.x; wh[4*q+1] = v.y; wh[4*q+2] = v.z; wh[4*q+3] = v.w;
        }
    }

    float c = 0.0f;
    if (j < H) {
        lds_h[j] = (t0 == 0) ? h0in[(size_t)NB * H + (size_t)b * H + j]
                             : st_h[(size_t)b * H + j];
        c        = (t0 == 0) ? 0.0f : st_c[(size_t)b * H + j];
    }
    __syncthreads();

    float xg_next = xg[((size_t)b * ntile + 0) * G4 + j];

    for (int tt = 0; tt < ntile; ++tt) {
        const float hv0 = lds_h[lane];
        const float hv1 = lds_h[64 + lane];
        const float g0  = xg_next;
        if (tt + 1 < ntile) xg_next = xg[((size_t)b * ntile + tt + 1) * G4 + j];

        float a0 = 0.f, a1 = 0.f, a2 = 0.f, a3 = 0.f;
        #pragma unroll
        for (int k = 0; k < 64; k += 4) {
            a0 += wh[k]   * bcast(hv0, k);
            a1 += wh[k+1] * bcast(hv0, k+1);
            a2 += wh[k+2] * bcast(hv0, k+2);
            a3 += wh[k+3] * bcast(hv0, k+3);
        }
        #pragma unroll
        for (int k = 0; k < 64; k += 4) {
            a0 += wh[64+k]   * bcast(hv1, k);
            a1 += wh[64+k+1] * bcast(hv1, k+1);
            a2 += wh[64+k+2] * bcast(hv1, k+2);
            a3 += wh[64+k+3] * bcast(hv1, k+3);
        }
        lds_g[j] = g0 + ((a0 + a1) + (a2 + a3));
        __syncthreads();

        if (j < H) {
            float gi = lds_g[j], gf = lds_g[H + j], gg = lds_g[2*H + j], go = lds_g[3*H + j];
            c = sigf(gf) * c + sigf(gi) * tanhf_(gg);
            lds_h[j] = sigf(go) * tanhf_(c);
        }
        __syncthreads();
    }

    if (j < H) {
        st_h[(size_t)b * H + j] = lds_h[j];
        st_c[(size_t)b * H + j] = c;
    }

    if (t0 + ntile == T) {   // fused FC on final h
        if (j < H) lds_g[j] = lds_h[j] * fcw[j];
        __syncthreads();
        if (j == 0) {
            float s = fcb[0];
            for (int k = 0; k < H; ++k) s += lds_g[k];
            out[b] = s;
        }
    }
}

extern "C" void kernel_launch(void* const* d_in, const int* in_sizes, int n_in,
                              void* d_out, int out_size, void* d_ws, size_t ws_size,
                              hipStream_t stream)
{
    const float* x    = (const float*)d_in[0];
    const float* h0   = (const float*)d_in[1];
    const float* wih0 = (const float*)d_in[2];
    const float* whh0 = (const float*)d_in[3];
    const float* b0   = (const float*)d_in[4];
    const float* wih1 = (const float*)d_in[5];
    const float* whh1 = (const float*)d_in[6];
    const float* b1   = (const float*)d_in[7];
    const float* fcw  = (const float*)d_in[8];
    const float* fcb  = (const float*)d_in[9];
    float* out = (float*)d_out;

    // choose time-tile so ws fits: h0_tile + xg_tile + 4 state buffers
    int TILE = 128;
    while (TILE > 8) {
        size_t need = (size_t)NB * TILE * H * 4 + (size_t)NB * TILE * G4 * 4
                    + 4 * (size_t)NB * H * 4;
        if (need <= ws_size) break;
        TILE >>= 1;
    }

    float* h0_tile = (float*)d_ws;
    float* xg_tile = h0_tile + (size_t)NB * TILE * H;
    float* st_h0   = xg_tile + (size_t)NB * TILE * G4;
    float* st_c0   = st_h0 + (size_t)NB * H;
    float* st_h1   = st_c0 + (size_t)NB * H;
    float* st_c1   = st_h1 + (size_t)NB * H;

    for (int t0 = 0; t0 < T; t0 += TILE) {
        scan_l0_tile<<<NB, 512, 0, stream>>>(x, h0, wih0, whh0, b0,
                                             h0_tile, st_h0, st_c0, t0, TILE);
        xg1_tile<<<(NB * TILE) / 64, 512, 0, stream>>>(h0_tile, wih1, b1, xg_tile);
        scan_l1_tile<<<NB, 512, 0, stream>>>(xg_tile, h0, whh1, fcw, fcb, out,
                                             st_h1, st_c1, t0, TILE);
    }
}

// Round 3
// 3434.509 us; speedup vs baseline: 5.2732x; 1.0963x over previous
//
#include <hip/hip_runtime.h>
#include <math.h>

#define NB  256
#define T   1024
#define DIN 64
#define H   128
#define G4  512

typedef __attribute__((ext_vector_type(8))) short bf16x8;
typedef __attribute__((ext_vector_type(4))) float f32x4;

__device__ __forceinline__ float bcast(float v, int l) {
    return __int_as_float(__builtin_amdgcn_readlane(__float_as_int(v), l));
}
// quad_perm broadcast of lane (quadbase+L) -> all 4 lanes of quad
#define QBC(v, CTRL) __int_as_float(__builtin_amdgcn_update_dpp(0, __float_as_int(v), (CTRL), 0xf, 0xf, true))

__device__ __forceinline__ float sigf(float x)   { return 1.0f / (1.0f + __expf(-x)); }
__device__ __forceinline__ float tanhf_(float x) { return 2.0f / (1.0f + __expf(-2.0f * x)) - 1.0f; }

// round-to-nearest-even split x = hi + lo (both bf16), residual ~2^-17 rel
__device__ __forceinline__ void split_bf16(float x, short& hi, short& lo) {
    unsigned u = __float_as_uint(x);
    unsigned hb = (u + 0x7fffu + ((u >> 16) & 1u)) >> 16;
    hi = (short)hb;
    float r = x - __uint_as_float(hb << 16);
    unsigned u2 = __float_as_uint(r);
    lo = (short)((u2 + 0x7fffu + ((u2 >> 16) & 1u)) >> 16);
}

// ---------------------------------------------------------------------------
// Recurrent scan over one time tile, one layer. grid=256 (batch), 512 thr.
// Thread j owns gate' j = 4*hu + type (type: 0=i,1=f,2=g,3=o), i.e. original
// gate row perm(j) = (j&3)*128 + (j>>2). All four gates of hu live in one
// quad -> c/h update via 3 DPP quad_perm movs, no LDS, no wave asymmetry.
// lds_h double-buffered -> ONE barrier per step.
// ---------------------------------------------------------------------------
__global__ __launch_bounds__(512, 2)
void scan_tile(const float* __restrict__ xg,    // [NB*TILE][512] gate' order, no bias
               const float* __restrict__ whh,   // [512][128] original order
               const float* __restrict__ bias,  // [512] original order
               const float* __restrict__ h0in,  // [NB][128] this layer's h0
               float* __restrict__ st_h, float* __restrict__ st_c,  // [NB][128]
               float* __restrict__ h0out,       // l0: [NB*TILE][128] (else null)
               const float* __restrict__ fcw, const float* __restrict__ fcb,
               float* __restrict__ out,
               int t0, int TILE, int do_fc)
{
    __shared__ __align__(16) float lds_h[2][H];
    __shared__ __align__(16) float lds_r[H];

    const int j    = threadIdx.x;
    const int b    = blockIdx.x;
    const int lane = j & 63;
    const int hu   = j >> 2;
    const int typ  = j & 3;
    const int pj   = typ * 128 + hu;     // original gate row

    float wh[H];
    {
        const float4* p = (const float4*)(whh + (size_t)pj * H);
        #pragma unroll
        for (int q = 0; q < H / 4; ++q) {
            float4 v = p[q];
            wh[4*q] = v.x; wh[4*q+1] = v.y; wh[4*q+2] = v.z; wh[4*q+3] = v.w;
        }
    }
    const float bj = bias[pj];

    float c;
    if (t0 == 0) {
        if (j < H) lds_h[0][j] = h0in[(size_t)b * H + j];
        c = 0.0f;
    } else {
        if (j < H) lds_h[0][j] = st_h[(size_t)b * H + j];
        c = st_c[(size_t)b * H + hu];
    }
    __syncthreads();

    float xgv = xg[((size_t)b * TILE) * G4 + j];
    float hreg = 0.0f;
    int cur = 0;

    for (int tt = 0; tt < TILE; ++tt) {
        const float hv0 = lds_h[cur][lane];
        const float hv1 = lds_h[cur][64 + lane];
        float xgn = 0.0f;
        if (tt + 1 < TILE) xgn = xg[((size_t)b * TILE + tt + 1) * G4 + j];

        float a0 = 0.f, a1 = 0.f, a2 = 0.f, a3 = 0.f;
        float a4 = 0.f, a5 = 0.f, a6 = 0.f, a7 = 0.f;
        #pragma unroll
        for (int k = 0; k < 64; k += 8) {
            a0 += wh[k+0] * bcast(hv0, k+0);
            a1 += wh[k+1] * bcast(hv0, k+1);
            a2 += wh[k+2] * bcast(hv0, k+2);
            a3 += wh[k+3] * bcast(hv0, k+3);
            a4 += wh[k+4] * bcast(hv0, k+4);
            a5 += wh[k+5] * bcast(hv0, k+5);
            a6 += wh[k+6] * bcast(hv0, k+6);
            a7 += wh[k+7] * bcast(hv0, k+7);
        }
        #pragma unroll
        for (int k = 0; k < 64; k += 8) {
            a0 += wh[64+k+0] * bcast(hv1, k+0);
            a1 += wh[64+k+1] * bcast(hv1, k+1);
            a2 += wh[64+k+2] * bcast(hv1, k+2);
            a3 += wh[64+k+3] * bcast(hv1, k+3);
            a4 += wh[64+k+4] * bcast(hv1, k+4);
            a5 += wh[64+k+5] * bcast(hv1, k+5);
            a6 += wh[64+k+6] * bcast(hv1, k+6);
            a7 += wh[64+k+7] * bcast(hv1, k+7);
        }
        float g = xgv + bj + (((a0+a1)+(a2+a3)) + ((a4+a5)+(a6+a7)));

        // quad exchange: all 4 lanes get i,f,g,o
        float gi = QBC(g, 0x00);
        float gf = QBC(g, 0x55);
        float gg = QBC(g, 0xAA);
        float go = QBC(g, 0xFF);

        c = sigf(gf) * c + sigf(gi) * tanhf_(gg);
        float h = sigf(go) * tanhf_(c);
        hreg = h;

        if (typ == 0) {
            lds_h[cur ^ 1][hu] = h;
            if (h0out) h0out[((size_t)b * TILE + tt) * H + hu] = h;
        }
        xgv = xgn;
        cur ^= 1;
        __syncthreads();
    }

    if (typ == 0) {
        st_h[(size_t)b * H + hu] = hreg;
        st_c[(size_t)b * H + hu] = c;
    }

    if (do_fc) {
        if (typ == 0) lds_r[hu] = hreg * fcw[hu];
        __syncthreads();
        if (j == 0) {
            float s = fcb[0];
            for (int k = 0; k < H; ++k) s += lds_r[k];
            out[b] = s;
        }
    }
}

// ---------------------------------------------------------------------------
// MFMA GEMM: Out[r][n'] = sum_k A[r][k] * W[perm(n')][k]   (no bias; fp32 in/out)
// bf16 3-term split (Ah*Wh + Al*Wh + Ah*Wl), 16x16x32 MFMA.
// Block 256 thr (4 waves, 2x2), tile 128x128, BK=64 two-pass. Dual-job launch.
// A row r -> global row (r>>lgT)*Astride + t0 + (r&(TILE-1)).
// ---------------------------------------------------------------------------
__global__ __launch_bounds__(256, 2)
void gemm_xg(const float* __restrict__ A0, const float* __restrict__ W0,
             float* __restrict__ O0, int K0, int Astride0, int t00,
             const float* __restrict__ A1, const float* __restrict__ W1,
             float* __restrict__ O1, int K1, int Astride1, int t01,
             int nbA, int lgT, int lgM)
{
    __shared__ short Ah[128][72], Al[128][72], Wh[128][72], Wl[128][72]; // 72 KB

    const float* A; const float* W; float* O; int K, Astride, t0;
    int bid = blockIdx.x;
    if (bid < nbA) { A = A0; W = W0; O = O0; K = K0; Astride = Astride0; t0 = t00; }
    else { bid -= nbA; A = A1; W = W1; O = O1; K = K1; Astride = Astride1; t0 = t01; }

    const int Mmask = (1 << lgM) - 1;
    const int m0 = (bid & Mmask) << 7;
    const int n0 = (bid >> lgM) << 7;
    const int TILEm = 1 << lgT, Tmask = TILEm - 1;

    const int j = threadIdx.x;
    const int lane = j & 63, wv = j >> 6;
    const int wm = wv >> 1, wn = wv & 1;
    const int q = lane >> 4, n16 = lane & 15;

    f32x4 acc[4][4];
    #pragma unroll
    for (int a = 0; a < 4; ++a)
        #pragma unroll
        for (int bq = 0; bq < 4; ++bq) acc[a][bq] = (f32x4){0.f, 0.f, 0.f, 0.f};

    const int npass = K >> 6;
    for (int kp = 0; kp < npass; ++kp) {
        // stage A tile rows m0..m0+127, k in [kp*64, kp*64+64)
        #pragma unroll
        for (int it = 0; it < 8; ++it) {
            int cidx = j + it * 256;            // 2048 chunks of 4 floats
            int r = cidx >> 4, kc = (cidx & 15) << 2;
            int gr = m0 + r;
            size_t arow = (size_t)(gr >> lgT) * Astride + t0 + (gr & Tmask);
            float4 v = *(const float4*)(A + arow * K + kp * 64 + kc);
            short h0s, l0s, h1s, l1s, h2s, l2s, h3s, l3s;
            split_bf16(v.x, h0s, l0s); split_bf16(v.y, h1s, l1s);
            split_bf16(v.z, h2s, l2s); split_bf16(v.w, h3s, l3s);
            *(short4*)&Ah[r][kc] = make_short4(h0s, h1s, h2s, h3s);
            *(short4*)&Al[r][kc] = make_short4(l0s, l1s, l2s, l3s);
        }
        // stage W tile rows perm(n0..n0+127)
        #pragma unroll
        for (int it = 0; it < 8; ++it) {
            int cidx = j + it * 256;
            int r = cidx >> 4, kc = (cidx & 15) << 2;
            int n = n0 + r;
            int pn = (n & 3) * 128 + (n >> 2);
            float4 v = *(const float4*)(W + (size_t)pn * K + kp * 64 + kc);
            short h0s, l0s, h1s, l1s, h2s, l2s, h3s, l3s;
            split_bf16(v.x, h0s, l0s); split_bf16(v.y, h1s, l1s);
            split_bf16(v.z, h2s, l2s); split_bf16(v.w, h3s, l3s);
            *(short4*)&Wh[r][kc] = make_short4(h0s, h1s, h2s, h3s);
            *(short4*)&Wl[r][kc] = make_short4(l0s, l1s, l2s, l3s);
        }
        __syncthreads();

        #pragma unroll
        for (int kt = 0; kt < 2; ++kt) {
            const int kk = kt * 32 + q * 8;
            bf16x8 ah[4], al[4];
            #pragma unroll
            for (int mt = 0; mt < 4; ++mt) {
                int row = wm * 64 + mt * 16 + n16;
                ah[mt] = *(const bf16x8*)&Ah[row][kk];
                al[mt] = *(const bf16x8*)&Al[row][kk];
            }
            #pragma unroll
            for (int nt = 0; nt < 4; ++nt) {
                int col = wn * 64 + nt * 16 + n16;
                bf16x8 bh = *(const bf16x8*)&Wh[col][kk];
                bf16x8 bl = *(const bf16x8*)&Wl[col][kk];
                #pragma unroll
                for (int mt = 0; mt < 4; ++mt) {
                    acc[mt][nt] = __builtin_amdgcn_mfma_f32_16x16x32_bf16(ah[mt], bh, acc[mt][nt], 0, 0, 0);
                    acc[mt][nt] = __builtin_amdgcn_mfma_f32_16x16x32_bf16(al[mt], bh, acc[mt][nt], 0, 0, 0);
                    acc[mt][nt] = __builtin_amdgcn_mfma_f32_16x16x32_bf16(ah[mt], bl, acc[mt][nt], 0, 0, 0);
                }
            }
        }
        __syncthreads();
    }

    // epilogue: D row=(q*4+r), col=n16 within 16x16 tile
    #pragma unroll
    for (int mt = 0; mt < 4; ++mt) {
        #pragma unroll
        for (int nt = 0; nt < 4; ++nt) {
            int row = m0 + wm * 64 + mt * 16 + q * 4;
            int col = n0 + wn * 64 + nt * 16 + n16;
            #pragma unroll
            for (int r = 0; r < 4; ++r)
                O[(size_t)(row + r) * G4 + col] = acc[mt][nt][r];
        }
    }
}

extern "C" void kernel_launch(void* const* d_in, const int* in_sizes, int n_in,
                              void* d_out, int out_size, void* d_ws, size_t ws_size,
                              hipStream_t stream)
{
    const float* x    = (const float*)d_in[0];
    const float* h0   = (const float*)d_in[1];
    const float* wih0 = (const float*)d_in[2];
    const float* whh0 = (const float*)d_in[3];
    const float* b0   = (const float*)d_in[4];
    const float* wih1 = (const float*)d_in[5];
    const float* whh1 = (const float*)d_in[6];
    const float* b1   = (const float*)d_in[7];
    const float* fcw  = (const float*)d_in[8];
    const float* fcb  = (const float*)d_in[9];
    float* out = (float*)d_out;

    // adaptive time tile: xg0 slab + xg1 slab + h0 slab + 4 state arrays
    int TILE = 256, lgT = 8;
    while (TILE > 16) {
        size_t need = (size_t)TILE * NB * (2 * G4 + H) * 4 + (size_t)4 * NB * H * 4;
        if (need <= ws_size) break;
        TILE >>= 1; lgT--;
    }
    const int n_t = T / TILE;
    const int lgM = lgT + 1;                 // Mblocks = NB*TILE/128 = 2*TILE
    const int nbJ = (2 * TILE) * 4;          // blocks per gemm job

    float* xg0 = (float*)d_ws;                               // [NB*TILE][512]
    float* xg1 = xg0 + (size_t)NB * TILE * G4;               // [NB*TILE][512]
    float* h0s = xg1 + (size_t)NB * TILE * G4;               // [NB*TILE][128]
    float* st_h0 = h0s + (size_t)NB * TILE * H;
    float* st_c0 = st_h0 + (size_t)NB * H;
    float* st_h1 = st_c0 + (size_t)NB * H;
    float* st_c1 = st_h1 + (size_t)NB * H;

    // prologue: xg0 for tile 0
    gemm_xg<<<nbJ, 256, 0, stream>>>(x, wih0, xg0, DIN, T, 0,
                                     x, wih0, xg0, DIN, T, 0,
                                     nbJ, lgT, lgM);

    for (int k = 0; k < n_t; ++k) {
        int t0 = k * TILE;
        scan_tile<<<NB, 512, 0, stream>>>(xg0, whh0, b0, h0, st_h0, st_c0,
                                          h0s, fcw, fcb, out, t0, TILE, 0);
        // job A: xg1(k) from h0s; job B: xg0(k+1) from x (if any)
        int haveB = (k + 1 < n_t);
        gemm_xg<<<nbJ * (1 + haveB), 256, 0, stream>>>(
            h0s, wih1, xg1, H, TILE, 0,
            x, wih0, xg0, DIN, T, (k + 1) * TILE,
            nbJ, lgT, lgM);
        scan_tile<<<NB, 512, 0, stream>>>(xg1, whh1, b1, h0 + (size_t)NB * H,
                                          st_h1, st_c1, nullptr, fcw, fcb, out,
                                          t0, TILE, (k == n_t - 1) ? 1 : 0);
    }
}

// Round 4
// 2315.015 us; speedup vs baseline: 7.8232x; 1.4836x over previous
//
#include <hip/hip_runtime.h>
#include <math.h>

#define NB  256
#define T   1024
#define DIN 64
#define H   128
#define G4  512

typedef __attribute__((ext_vector_type(8))) short bf16x8;
typedef __attribute__((ext_vector_type(4))) float f32x4;

// quad_perm DPP: result = src from lane (quad_base + sel[lane&3]); all lanes active
#define DPPQ(v, CTRL) __int_as_float(__builtin_amdgcn_update_dpp(0, __float_as_int(v), (CTRL), 0xf, 0xf, true))
#define DPP_X1 0xB1   // quad_perm(1,0,3,2): xor lane^1
#define DPP_X2 0x4E   // quad_perm(2,3,0,1): xor lane^2

__device__ __forceinline__ float sigf(float x)   { return 1.0f / (1.0f + __expf(-x)); }
__device__ __forceinline__ float tanhf_(float x) { return 2.0f / (1.0f + __expf(-2.0f * x)) - 1.0f; }

// round-to-nearest-even split x = hi + lo (both bf16)
__device__ __forceinline__ void split_bf16(float x, short& hi, short& lo) {
    unsigned u = __float_as_uint(x);
    unsigned hb = (u + 0x7fffu + ((u >> 16) & 1u)) >> 16;
    hi = (short)hb;
    float r = x - __uint_as_float(hb << 16);
    unsigned u2 = __float_as_uint(r);
    lo = (short)((u2 + 0x7fffu + ((u2 >> 16) & 1u)) >> 16);
}

// ---------------------------------------------------------------------------
// Recurrent scan, one layer, one time tile. grid=256 (batch), 512 threads.
// Thread t = (hu = t>>2, kg = t&3): owns all 4 gates of hidden unit hu over
// k-chunk [32*kg, 32*kg+32). Per step: 8 ds_read_b128 of its h-chunk (padded
// chunk layout -> conflict-free), 128 fp32 FMAs into 4 partials, quad
// transpose-reduce via 3 DPP xor-adds (lane kg ends holding gate kg of hu =
// xg column t -> coalesced xg add), DPP gate exchange + nonlinearity.
// ONE barrier/step; h double-buffered in LDS. No readlane, no broadcast.
// ---------------------------------------------------------------------------
__global__ __launch_bounds__(512, 2)
void scan_tile(const float* __restrict__ xg,    // [NB*TILE][512] gate' order (4*hu+type), no bias
               const float* __restrict__ whh,   // [512][128] original gate order
               const float* __restrict__ bias,  // [512] original order
               const float* __restrict__ h0in,  // [NB][128] this layer's h0
               float* __restrict__ st_h, float* __restrict__ st_c,  // [NB][128]
               float* __restrict__ h0out,       // layer0: [NB*TILE][128] (else null)
               const float* __restrict__ fcw, const float* __restrict__ fcb,
               float* __restrict__ out,
               int t0, int TILE, int do_fc)
{
    // padded h chunks: chunk kg at word offset kg*36 -> banks 4*kg+4i disjoint
    __shared__ float lds_h[2][4][36];
    __shared__ float lds_r[H];

    const int t  = threadIdx.x;
    const int b  = blockIdx.x;
    const int kg = t & 3;
    const int hu = t >> 2;

    // weights: 4 gate rows of hu, k in [32*kg, 32*kg+32)
    float wh[4][32];
    #pragma unroll
    for (int g = 0; g < 4; ++g) {
        const float4* p = (const float4*)(whh + (size_t)(g * 128 + hu) * H + kg * 32);
        #pragma unroll
        for (int q = 0; q < 8; ++q) {
            float4 v = p[q];
            wh[g][4*q] = v.x; wh[g][4*q+1] = v.y; wh[g][4*q+2] = v.z; wh[g][4*q+3] = v.w;
        }
    }
    const float bj = bias[kg * 128 + hu];

    // init h buffer 0 (chunk layout) and c
    if (t < H) {
        float hv = (t0 == 0) ? h0in[(size_t)b * H + t] : st_h[(size_t)b * H + t];
        lds_h[0][t >> 5][t & 31] = hv;
    }
    float c = (t0 == 0) ? 0.0f : st_c[(size_t)b * H + hu];
    __syncthreads();

    // xg prefetch, depth 2
    const float* xgb = xg + (size_t)b * TILE * G4 + t;
    float xv0 = xgb[0];
    float xv1 = (TILE > 1) ? xgb[G4] : 0.0f;

    float hreg = 0.0f;
    int cur = 0;

    for (int tt = 0; tt < TILE; ++tt) {
        // load this thread's 32-float h chunk
        float hr[32];
        const float* hc = &lds_h[cur][kg][0];
        #pragma unroll
        for (int q = 0; q < 8; ++q) {
            float4 v = *(const float4*)(hc + 4 * q);
            hr[4*q] = v.x; hr[4*q+1] = v.y; hr[4*q+2] = v.z; hr[4*q+3] = v.w;
        }

        // 4 partial gate dots over this k-chunk (4 independent FMA chains)
        float p0a = 0.f, p1a = 0.f, p2a = 0.f, p3a = 0.f;
        #pragma unroll
        for (int i = 0; i < 32; ++i) {
            p0a += wh[0][i] * hr[i];
            p1a += wh[1][i] * hr[i];
            p2a += wh[2][i] * hr[i];
            p3a += wh[3][i] * hr[i];
        }

        // quad transpose-reduce: lane kg ends with gate kg of hu
        const bool q0 = (kg & 1) != 0;
        const bool q1 = (kg & 2) != 0;
        float keepA = q0 ? p1a : p0a, sendA = q0 ? p0a : p1a;
        float A  = keepA + DPPQ(sendA, DPP_X1);      // gate (q0) over kg-pair
        float keepB = q0 ? p3a : p2a, sendB = q0 ? p2a : p3a;
        float Bv = keepB + DPPQ(sendB, DPP_X1);      // gate (2+q0) over kg-pair
        float keep = q1 ? Bv : A, send = q1 ? A : Bv;
        float g = keep + DPPQ(send, DPP_X2);         // gate kg, full sum

        g += xv0 + bj;

        // rotate prefetch
        xv0 = xv1;
        if (tt + 2 < TILE) xv1 = xgb[(size_t)(tt + 2) * G4];

        // quad exchange: all lanes get i,f,g,o of hu
        float gi = DPPQ(g, 0x00);
        float gf = DPPQ(g, 0x55);
        float gg = DPPQ(g, 0xAA);
        float go = DPPQ(g, 0xFF);

        c = sigf(gf) * c + sigf(gi) * tanhf_(gg);
        float h = sigf(go) * tanhf_(c);
        hreg = h;

        if (kg == 0) {
            lds_h[cur ^ 1][hu >> 5][hu & 31] = h;
            if (h0out) h0out[((size_t)b * TILE + tt) * H + hu] = h;
        }
        cur ^= 1;
        __syncthreads();
    }

    if (kg == 0) {
        st_h[(size_t)b * H + hu] = hreg;
        st_c[(size_t)b * H + hu] = c;
    }

    if (do_fc) {
        if (kg == 0) lds_r[hu] = hreg * fcw[hu];
        __syncthreads();
        if (t == 0) {
            float s = fcb[0];
            for (int k = 0; k < H; ++k) s += lds_r[k];
            out[b] = s;
        }
    }
}

// ---------------------------------------------------------------------------
// MFMA GEMM: Out[r][n'] = sum_k A[r][k] * W[perm(n')][k]   (no bias; fp32 in/out)
// bf16 3-term split (Ah*Wh + Al*Wh + Ah*Wl), 16x16x32 MFMA.
// Block 256 thr (4 waves, 2x2), tile 128x128, BK=64 two-pass. Dual-job launch.
// ---------------------------------------------------------------------------
__global__ __launch_bounds__(256, 2)
void gemm_xg(const float* __restrict__ A0, const float* __restrict__ W0,
             float* __restrict__ O0, int K0, int Astride0, int t00,
             const float* __restrict__ A1, const float* __restrict__ W1,
             float* __restrict__ O1, int K1, int Astride1, int t01,
             int nbA, int lgT, int lgM)
{
    __shared__ short Ah[128][72], Al[128][72], Wh[128][72], Wl[128][72]; // 72 KB

    const float* A; const float* W; float* O; int K, Astride, t0;
    int bid = blockIdx.x;
    if (bid < nbA) { A = A0; W = W0; O = O0; K = K0; Astride = Astride0; t0 = t00; }
    else { bid -= nbA; A = A1; W = W1; O = O1; K = K1; Astride = Astride1; t0 = t01; }

    const int Mmask = (1 << lgM) - 1;
    const int m0 = (bid & Mmask) << 7;
    const int n0 = (bid >> lgM) << 7;
    const int TILEm = 1 << lgT, Tmask = TILEm - 1;

    const int j = threadIdx.x;
    const int lane = j & 63, wv = j >> 6;
    const int wm = wv >> 1, wn = wv & 1;
    const int q = lane >> 4, n16 = lane & 15;

    f32x4 acc[4][4];
    #pragma unroll
    for (int a = 0; a < 4; ++a)
        #pragma unroll
        for (int bq = 0; bq < 4; ++bq) acc[a][bq] = (f32x4){0.f, 0.f, 0.f, 0.f};

    const int npass = K >> 6;
    for (int kp = 0; kp < npass; ++kp) {
        #pragma unroll
        for (int it = 0; it < 8; ++it) {
            int cidx = j + it * 256;
            int r = cidx >> 4, kc = (cidx & 15) << 2;
            int gr = m0 + r;
            size_t arow = (size_t)(gr >> lgT) * Astride + t0 + (gr & Tmask);
            float4 v = *(const float4*)(A + arow * K + kp * 64 + kc);
            short h0s, l0s, h1s, l1s, h2s, l2s, h3s, l3s;
            split_bf16(v.x, h0s, l0s); split_bf16(v.y, h1s, l1s);
            split_bf16(v.z, h2s, l2s); split_bf16(v.w, h3s, l3s);
            *(short4*)&Ah[r][kc] = make_short4(h0s, h1s, h2s, h3s);
            *(short4*)&Al[r][kc] = make_short4(l0s, l1s, l2s, l3s);
        }
        #pragma unroll
        for (int it = 0; it < 8; ++it) {
            int cidx = j + it * 256;
            int r = cidx >> 4, kc = (cidx & 15) << 2;
            int n = n0 + r;
            int pn = (n & 3) * 128 + (n >> 2);
            float4 v = *(const float4*)(W + (size_t)pn * K + kp * 64 + kc);
            short h0s, l0s, h1s, l1s, h2s, l2s, h3s, l3s;
            split_bf16(v.x, h0s, l0s); split_bf16(v.y, h1s, l1s);
            split_bf16(v.z, h2s, l2s); split_bf16(v.w, h3s, l3s);
            *(short4*)&Wh[r][kc] = make_short4(h0s, h1s, h2s, h3s);
            *(short4*)&Wl[r][kc] = make_short4(l0s, l1s, l2s, l3s);
        }
        __syncthreads();

        #pragma unroll
        for (int kt = 0; kt < 2; ++kt) {
            const int kk = kt * 32 + q * 8;
            bf16x8 ah[4], al[4];
            #pragma unroll
            for (int mt = 0; mt < 4; ++mt) {
                int row = wm * 64 + mt * 16 + n16;
                ah[mt] = *(const bf16x8*)&Ah[row][kk];
                al[mt] = *(const bf16x8*)&Al[row][kk];
            }
            #pragma unroll
            for (int nt = 0; nt < 4; ++nt) {
                int col = wn * 64 + nt * 16 + n16;
                bf16x8 bh = *(const bf16x8*)&Wh[col][kk];
                bf16x8 bl = *(const bf16x8*)&Wl[col][kk];
                #pragma unroll
                for (int mt = 0; mt < 4; ++mt) {
                    acc[mt][nt] = __builtin_amdgcn_mfma_f32_16x16x32_bf16(ah[mt], bh, acc[mt][nt], 0, 0, 0);
                    acc[mt][nt] = __builtin_amdgcn_mfma_f32_16x16x32_bf16(al[mt], bh, acc[mt][nt], 0, 0, 0);
                    acc[mt][nt] = __builtin_amdgcn_mfma_f32_16x16x32_bf16(ah[mt], bl, acc[mt][nt], 0, 0, 0);
                }
            }
        }
        __syncthreads();
    }

    #pragma unroll
    for (int mt = 0; mt < 4; ++mt) {
        #pragma unroll
        for (int nt = 0; nt < 4; ++nt) {
            int row = m0 + wm * 64 + mt * 16 + q * 4;
            int col = n0 + wn * 64 + nt * 16 + n16;
            #pragma unroll
            for (int r = 0; r < 4; ++r)
                O[(size_t)(row + r) * G4 + col] = acc[mt][nt][r];
        }
    }
}

extern "C" void kernel_launch(void* const* d_in, const int* in_sizes, int n_in,
                              void* d_out, int out_size, void* d_ws, size_t ws_size,
                              hipStream_t stream)
{
    const float* x    = (const float*)d_in[0];
    const float* h0   = (const float*)d_in[1];
    const float* wih0 = (const float*)d_in[2];
    const float* whh0 = (const float*)d_in[3];
    const float* b0   = (const float*)d_in[4];
    const float* wih1 = (const float*)d_in[5];
    const float* whh1 = (const float*)d_in[6];
    const float* b1   = (const float*)d_in[7];
    const float* fcw  = (const float*)d_in[8];
    const float* fcb  = (const float*)d_in[9];
    float* out = (float*)d_out;

    int TILE = 256, lgT = 8;
    while (TILE > 16) {
        size_t need = (size_t)TILE * NB * (2 * G4 + H) * 4 + (size_t)4 * NB * H * 4;
        if (need <= ws_size) break;
        TILE >>= 1; lgT--;
    }
    const int n_t = T / TILE;
    const int lgM = lgT + 1;
    const int nbJ = (2 * TILE) * 4;

    float* xg0 = (float*)d_ws;
    float* xg1 = xg0 + (size_t)NB * TILE * G4;
    float* h0s = xg1 + (size_t)NB * TILE * G4;
    float* st_h0 = h0s + (size_t)NB * TILE * H;
    float* st_c0 = st_h0 + (size_t)NB * H;
    float* st_h1 = st_c0 + (size_t)NB * H;
    float* st_c1 = st_h1 + (size_t)NB * H;

    gemm_xg<<<nbJ, 256, 0, stream>>>(x, wih0, xg0, DIN, T, 0,
                                     x, wih0, xg0, DIN, T, 0,
                                     nbJ, lgT, lgM);

    for (int k = 0; k < n_t; ++k) {
        int t0 = k * TILE;
        scan_tile<<<NB, 512, 0, stream>>>(xg0, whh0, b0, h0, st_h0, st_c0,
                                          h0s, fcw, fcb, out, t0, TILE, 0);
        int haveB = (k + 1 < n_t);
        gemm_xg<<<nbJ * (1 + haveB), 256, 0, stream>>>(
            h0s, wih1, xg1, H, TILE, 0,
            x, wih0, xg0, DIN, T, (k + 1) * TILE,
            nbJ, lgT, lgM);
        scan_tile<<<NB, 512, 0, stream>>>(xg1, whh1, b1, h0 + (size_t)NB * H,
                                          st_h1, st_c1, nullptr, fcw, fcb, out,
                                          t0, TILE, (k == n_t - 1) ? 1 : 0);
    }
}

// Round 6
// 2049.158 us; speedup vs baseline: 8.8382x; 1.1297x over previous
//
#include <hip/hip_runtime.h>
#include <math.h>

#define NB  256
#define T   1024
#define DIN 64
#define H   128
#define G4  512

typedef __attribute__((ext_vector_type(8))) short    bf16x8;
typedef __attribute__((ext_vector_type(4))) float    f32x4;
typedef __attribute__((ext_vector_type(2))) _Float16 f16x2;
typedef __attribute__((ext_vector_type(4))) _Float16 f16x4;
typedef __attribute__((ext_vector_type(8))) _Float16 f16x8;

#define DPPQ(v, CTRL) __int_as_float(__builtin_amdgcn_update_dpp(0, __float_as_int(v), (CTRL), 0xf, 0xf, true))
#define DPP_X1 0xB1   // quad_perm(1,0,3,2)
#define DPP_X2 0x4E   // quad_perm(2,3,0,1)

__device__ __forceinline__ float sigf(float x)   { return 1.0f / (1.0f + __expf(-x)); }
__device__ __forceinline__ float tanhf_(float x) { return 2.0f / (1.0f + __expf(-2.0f * x)) - 1.0f; }

__device__ __forceinline__ void split_bf16(float x, short& hi, short& lo) {
    unsigned u = __float_as_uint(x);
    unsigned hb = (u + 0x7fffu + ((u >> 16) & 1u)) >> 16;
    hi = (short)hb;
    float r = x - __uint_as_float(hb << 16);
    unsigned u2 = __float_as_uint(r);
    lo = (short)((u2 + 0x7fffu + ((u2 >> 16) & 1u)) >> 16);
}

struct SJ {                       // one scan job (one layer, one time tile)
    const float* xg;              // [NB*TILE][512] gate' order, no bias
    const float* whh;             // [512][128] original gate order
    const float* bias;            // [512] original order
    const float* h0;              // [NB][128] initial h for this layer
    float* sth; float* stc;       // [NB][128] carried state
    _Float16* hout;               // layer0: [NB*TILE][128] f16 (else null)
    int first;                    // t0 == 0 ?
    int dofc;                     // fuse final FC (layer1 last tile)
};

// 4 dot2's for pair I (LITERAL) of an f16x8 chunk, weight base BASE
#define DOT4(H8, BASE, I)                                                      \
    do {                                                                       \
        f16x2 hp = __builtin_shufflevector((H8), (H8), 2*(I), 2*(I)+1);        \
        p0 = __builtin_amdgcn_fdot2(wv[0][(BASE)+(I)], hp, p0, false);         \
        p1 = __builtin_amdgcn_fdot2(wv[1][(BASE)+(I)], hp, p1, false);         \
        p2 = __builtin_amdgcn_fdot2(wv[2][(BASE)+(I)], hp, p2, false);         \
        p3 = __builtin_amdgcn_fdot2(wv[3][(BASE)+(I)], hp, p3, false);         \
    } while (0)

// ---------------------------------------------------------------------------
// Dual-job recurrent scan. grid = nbA + nbB blocks, 512 threads.
// Thread t = (hu=t>>2, kg=t&3): 4 gates of hu over k-chunk [32kg,32kg+32).
// f16 dot2 (weights 64 f16x2 VGPRs, h f16 in LDS, conflict-free 80B-stride
// chunks), DPP quad transpose-reduce, DPP gate exchange, fp32 c/h.
// One barrier/step. <=128 VGPR so two blocks (two jobs) share a CU.
// ---------------------------------------------------------------------------
template<int TILE>
__global__ __launch_bounds__(512, 4)
void scan2(SJ ja, SJ jb, int nbA,
           const float* __restrict__ fcw, const float* __restrict__ fcb,
           float* __restrict__ out)
{
    __shared__ _Float16 __align__(16) lds_h[2][4][40];  // chunk kg at 80B stride
    __shared__ float lds_r[H];

    const int bid = blockIdx.x;
    const bool isA = bid < nbA;
    const SJ J = isA ? ja : jb;
    const int b = isA ? bid : bid - nbA;

    const int t  = threadIdx.x;
    const int kg = t & 3;
    const int hu = t >> 2;

    // weights -> f16 pairs (4 gates x 16 pairs = 64 VGPRs)
    f16x2 wv[4][16];
    #pragma unroll
    for (int g = 0; g < 4; ++g) {
        const float4* p = (const float4*)(J.whh + (size_t)(g * 128 + hu) * H + kg * 32);
        #pragma unroll
        for (int q = 0; q < 8; ++q) {
            float4 v = p[q];
            wv[g][2*q]   = (f16x2){(_Float16)v.x, (_Float16)v.y};
            wv[g][2*q+1] = (f16x2){(_Float16)v.z, (_Float16)v.w};
        }
    }
    const float bj = J.bias[kg * 128 + hu];

    if (t < H) {
        float hv = J.first ? J.h0[(size_t)b * H + t] : J.sth[(size_t)b * H + t];
        lds_h[0][t >> 5][t & 31] = (_Float16)hv;
    }
    float c = J.first ? 0.0f : J.stc[(size_t)b * H + hu];
    __syncthreads();

    const float* xgb = J.xg + (size_t)b * TILE * G4 + t;
    float xv0 = xgb[0];
    float xv1 = (TILE > 1) ? xgb[G4] : 0.0f;

    float hreg = 0.0f;
    int cur = 0;

    for (int tt = 0; tt < TILE; ++tt) {
        // 4 conflict-free b128 broadcast reads of this thread's f16 h-chunk
        const f16x8* hc = (const f16x8*)&lds_h[cur][kg][0];
        f16x8 h8a = hc[0], h8b = hc[1], h8c = hc[2], h8d = hc[3];

        float p0 = 0.f, p1 = 0.f, p2 = 0.f, p3 = 0.f;
        DOT4(h8a,  0, 0); DOT4(h8a,  0, 1); DOT4(h8a,  0, 2); DOT4(h8a,  0, 3);
        DOT4(h8b,  4, 0); DOT4(h8b,  4, 1); DOT4(h8b,  4, 2); DOT4(h8b,  4, 3);
        DOT4(h8c,  8, 0); DOT4(h8c,  8, 1); DOT4(h8c,  8, 2); DOT4(h8c,  8, 3);
        DOT4(h8d, 12, 0); DOT4(h8d, 12, 1); DOT4(h8d, 12, 2); DOT4(h8d, 12, 3);

        // quad transpose-reduce: lane kg ends with gate kg of hu
        const bool q0 = (kg & 1) != 0;
        const bool q1 = (kg & 2) != 0;
        float keepA = q0 ? p1 : p0, sendA = q0 ? p0 : p1;
        float A  = keepA + DPPQ(sendA, DPP_X1);
        float keepB = q0 ? p3 : p2, sendB = q0 ? p2 : p3;
        float Bv = keepB + DPPQ(sendB, DPP_X1);
        float keep = q1 ? Bv : A, send = q1 ? A : Bv;
        float g = keep + DPPQ(send, DPP_X2);

        g += xv0 + bj;

        xv0 = xv1;
        int tn = (tt + 2 < TILE) ? (tt + 2) : (TILE - 1);
        xv1 = xgb[(size_t)tn * G4];

        float gi = DPPQ(g, 0x00);
        float gf = DPPQ(g, 0x55);
        float gg = DPPQ(g, 0xAA);
        float go = DPPQ(g, 0xFF);

        c = sigf(gf) * c + sigf(gi) * tanhf_(gg);
        float h = sigf(go) * tanhf_(c);
        hreg = h;

        if (kg == 0) {
            lds_h[cur ^ 1][hu >> 5][hu & 31] = (_Float16)h;
            if (J.hout) J.hout[((size_t)b * TILE + tt) * H + hu] = (_Float16)h;
        }
        cur ^= 1;
        __syncthreads();
    }

    if (kg == 0) {
        J.sth[(size_t)b * H + hu] = hreg;
        J.stc[(size_t)b * H + hu] = c;
    }

    if (J.dofc) {
        if (kg == 0) lds_r[hu] = hreg * fcw[hu];
        __syncthreads();
        if (t == 0) {
            float s = fcb[0];
            for (int k = 0; k < H; ++k) s += lds_r[k];
            out[b] = s;
        }
    }
}

// ---------------------------------------------------------------------------
// MFMA GEMM: Out[r][n'] = sum_k A[r][k] * W[perm(n')][k]; bf16 3-term split.
// A may be fp32 or f16 (aHalf). Dual-job launch; tile 128x128, BK=64.
// ---------------------------------------------------------------------------
__global__ __launch_bounds__(256, 2)
void gemm_xg(const void* __restrict__ A0, const float* __restrict__ W0,
             float* __restrict__ O0, int K0, int As0, int t00, int aH0,
             const void* __restrict__ A1, const float* __restrict__ W1,
             float* __restrict__ O1, int K1, int As1, int t01, int aH1,
             int nbA, int lgT, int lgM)
{
    __shared__ short Ah[128][72], Al[128][72], Wh[128][72], Wl[128][72];

    const void* A; const float* W; float* O; int K, Astride, t0, aHalf;
    int bid = blockIdx.x;
    if (bid < nbA) { A = A0; W = W0; O = O0; K = K0; Astride = As0; t0 = t00; aHalf = aH0; }
    else { bid -= nbA; A = A1; W = W1; O = O1; K = K1; Astride = As1; t0 = t01; aHalf = aH1; }

    const int Mmask = (1 << lgM) - 1;
    const int m0 = (bid & Mmask) << 7;
    const int n0 = (bid >> lgM) << 7;
    const int Tmask = (1 << lgT) - 1;

    const int j = threadIdx.x;
    const int lane = j & 63, wv = j >> 6;
    const int wm = wv >> 1, wn = wv & 1;
    const int q = lane >> 4, n16 = lane & 15;

    f32x4 acc[4][4];
    #pragma unroll
    for (int a = 0; a < 4; ++a)
        #pragma unroll
        for (int bq = 0; bq < 4; ++bq) acc[a][bq] = (f32x4){0.f, 0.f, 0.f, 0.f};

    const int npass = K >> 6;
    for (int kp = 0; kp < npass; ++kp) {
        #pragma unroll
        for (int it = 0; it < 8; ++it) {
            int cidx = j + it * 256;
            int r = cidx >> 4, kc = (cidx & 15) << 2;
            int gr = m0 + r;
            size_t arow = (size_t)(gr >> lgT) * Astride + t0 + (gr & Tmask);
            float4 v;
            if (aHalf) {
                f16x4 hv4 = *(const f16x4*)((const _Float16*)A + arow * K + kp * 64 + kc);
                v = make_float4((float)hv4[0], (float)hv4[1], (float)hv4[2], (float)hv4[3]);
            } else {
                v = *(const float4*)((const float*)A + arow * K + kp * 64 + kc);
            }
            short h0s, l0s, h1s, l1s, h2s, l2s, h3s, l3s;
            split_bf16(v.x, h0s, l0s); split_bf16(v.y, h1s, l1s);
            split_bf16(v.z, h2s, l2s); split_bf16(v.w, h3s, l3s);
            *(short4*)&Ah[r][kc] = make_short4(h0s, h1s, h2s, h3s);
            *(short4*)&Al[r][kc] = make_short4(l0s, l1s, l2s, l3s);
        }
        #pragma unroll
        for (int it = 0; it < 8; ++it) {
            int cidx = j + it * 256;
            int r = cidx >> 4, kc = (cidx & 15) << 2;
            int n = n0 + r;
            int pn = (n & 3) * 128 + (n >> 2);
            float4 v = *(const float4*)(W + (size_t)pn * K + kp * 64 + kc);
            short h0s, l0s, h1s, l1s, h2s, l2s, h3s, l3s;
            split_bf16(v.x, h0s, l0s); split_bf16(v.y, h1s, l1s);
            split_bf16(v.z, h2s, l2s); split_bf16(v.w, h3s, l3s);
            *(short4*)&Wh[r][kc] = make_short4(h0s, h1s, h2s, h3s);
            *(short4*)&Wl[r][kc] = make_short4(l0s, l1s, l2s, l3s);
        }
        __syncthreads();

        #pragma unroll
        for (int kt = 0; kt < 2; ++kt) {
            const int kk = kt * 32 + q * 8;
            bf16x8 ah[4], al[4];
            #pragma unroll
            for (int mt = 0; mt < 4; ++mt) {
                int row = wm * 64 + mt * 16 + n16;
                ah[mt] = *(const bf16x8*)&Ah[row][kk];
                al[mt] = *(const bf16x8*)&Al[row][kk];
            }
            #pragma unroll
            for (int nt = 0; nt < 4; ++nt) {
                int col = wn * 64 + nt * 16 + n16;
                bf16x8 bh = *(const bf16x8*)&Wh[col][kk];
                bf16x8 bl = *(const bf16x8*)&Wl[col][kk];
                #pragma unroll
                for (int mt = 0; mt < 4; ++mt) {
                    acc[mt][nt] = __builtin_amdgcn_mfma_f32_16x16x32_bf16(ah[mt], bh, acc[mt][nt], 0, 0, 0);
                    acc[mt][nt] = __builtin_amdgcn_mfma_f32_16x16x32_bf16(al[mt], bh, acc[mt][nt], 0, 0, 0);
                    acc[mt][nt] = __builtin_amdgcn_mfma_f32_16x16x32_bf16(ah[mt], bl, acc[mt][nt], 0, 0, 0);
                }
            }
        }
        __syncthreads();
    }

    #pragma unroll
    for (int mt = 0; mt < 4; ++mt) {
        #pragma unroll
        for (int nt = 0; nt < 4; ++nt) {
            int row = m0 + wm * 64 + mt * 16 + q * 4;
            int col = n0 + wn * 64 + nt * 16 + n16;
            #pragma unroll
            for (int r = 0; r < 4; ++r)
                O[(size_t)(row + r) * G4 + col] = acc[mt][nt][r];
        }
    }
}

template<int TILE>
static void run_all(const float* x, const float* h0,
                    const float* wih0, const float* whh0, const float* b0,
                    const float* wih1, const float* whh1, const float* b1,
                    const float* fcw, const float* fcb, float* out,
                    void* d_ws, hipStream_t stream)
{
    const int n_t = T / TILE;
    const int lgT = __builtin_ctz(TILE);
    const int lgM = lgT + 1;
    const int nbJ = 8 * TILE;   // (NB*TILE/128) * (512/128)

    float*    xg0 = (float*)d_ws;
    float*    xg1 = xg0 + (size_t)NB * TILE * G4;
    _Float16* h0s = (_Float16*)(xg1 + (size_t)NB * TILE * G4);
    float*    st  = (float*)(h0s + (size_t)NB * TILE * H);
    float* st_h0 = st, *st_c0 = st + NB * H, *st_h1 = st + 2 * NB * H, *st_c1 = st + 3 * NB * H;

    SJ l0, l1;
    l0.whh = whh0; l0.bias = b0; l0.h0 = h0;               l0.sth = st_h0; l0.stc = st_c0;
    l0.xg = xg0;   l0.hout = h0s; l0.dofc = 0;
    l1.whh = whh1; l1.bias = b1; l1.h0 = h0 + (size_t)NB * H; l1.sth = st_h1; l1.stc = st_c1;
    l1.xg = xg1;   l1.hout = nullptr;

    // xg0(0)
    gemm_xg<<<nbJ, 256, 0, stream>>>(x, wih0, xg0, DIN, T, 0, 0,
                                     x, wih0, xg0, DIN, T, 0, 0, nbJ, lgT, lgM);
    // scan_l0 tile 0 (solo)
    l0.first = 1;
    scan2<TILE><<<NB, 512, 0, stream>>>(l0, l0, NB, fcw, fcb, out);

    for (int k = 0; k < n_t; ++k) {
        // gemm: xg1(k) from h0s (f16); plus xg0(k+1) from x if it exists
        if (k + 1 < n_t) {
            gemm_xg<<<2 * nbJ, 256, 0, stream>>>(
                h0s, wih1, xg1, H, TILE, 0, 1,
                x, wih0, xg0, DIN, T, (k + 1) * TILE, 0, nbJ, lgT, lgM);
            // combined: scan_l0(k+1) || scan_l1(k)
            l0.first = 0;
            l1.first = (k == 0);
            l1.dofc = 0;
            scan2<TILE><<<2 * NB, 512, 0, stream>>>(l0, l1, NB, fcw, fcb, out);
        } else {
            gemm_xg<<<nbJ, 256, 0, stream>>>(
                h0s, wih1, xg1, H, TILE, 0, 1,
                h0s, wih1, xg1, H, TILE, 0, 1, nbJ, lgT, lgM);
            // final scan_l1 (solo, fused FC)
            l1.first = (k == 0);
            l1.dofc = 1;
            scan2<TILE><<<NB, 512, 0, stream>>>(l1, l1, NB, fcw, fcb, out);
        }
    }
}

extern "C" void kernel_launch(void* const* d_in, const int* in_sizes, int n_in,
                              void* d_out, int out_size, void* d_ws, size_t ws_size,
                              hipStream_t stream)
{
    const float* x    = (const float*)d_in[0];
    const float* h0   = (const float*)d_in[1];
    const float* wih0 = (const float*)d_in[2];
    const float* whh0 = (const float*)d_in[3];
    const float* b0   = (const float*)d_in[4];
    const float* wih1 = (const float*)d_in[5];
    const float* whh1 = (const float*)d_in[6];
    const float* b1   = (const float*)d_in[7];
    const float* fcw  = (const float*)d_in[8];
    const float* fcb  = (const float*)d_in[9];
    float* out = (float*)d_out;

    int TILE = 256;
    while (TILE > 16) {
        size_t need = (size_t)NB * TILE * (2 * G4 * 4 + H * 2) + (size_t)4 * NB * H * 4;
        if (need <= ws_size) break;
        TILE >>= 1;
    }

    switch (TILE) {
        case 256: run_all<256>(x, h0, wih0, whh0, b0, wih1, whh1, b1, fcw, fcb, out, d_ws, stream); break;
        case 128: run_all<128>(x, h0, wih0, whh0, b0, wih1, whh1, b1, fcw, fcb, out, d_ws, stream); break;
        case  64: run_all< 64>(x, h0, wih0, whh0, b0, wih1, whh1, b1, fcw, fcb, out, d_ws, stream); break;
        default:  run_all< 32>(x, h0, wih0, whh0, b0, wih1, whh1, b1, fcw, fcb, out, d_ws, stream); break;
    }
}

// Round 7
// 1783.176 us; speedup vs baseline: 10.1565x; 1.1492x over previous
//
#include <hip/hip_runtime.h>
#include <math.h>

#define NB  256
#define T   1024
#define DIN 64
#define H   128
#define G4  512

typedef __attribute__((ext_vector_type(8))) short    bf16x8;
typedef __attribute__((ext_vector_type(4))) float    f32x4;
typedef __attribute__((ext_vector_type(4))) _Float16 f16x4;
typedef __attribute__((ext_vector_type(8))) _Float16 f16x8;

#define DPPQ(v, CTRL) __int_as_float(__builtin_amdgcn_update_dpp(0, __float_as_int(v), (CTRL), 0xf, 0xf, true))

__device__ __forceinline__ float sigf(float x)   { return 1.0f / (1.0f + __expf(-x)); }
__device__ __forceinline__ float tanhf_(float x) { return 2.0f / (1.0f + __expf(-2.0f * x)) - 1.0f; }

__device__ __forceinline__ void split_bf16(float x, short& hi, short& lo) {
    unsigned u = __float_as_uint(x);
    unsigned hb = (u + 0x7fffu + ((u >> 16) & 1u)) >> 16;
    hi = (short)hb;
    float r = x - __uint_as_float(hb << 16);
    unsigned u2 = __float_as_uint(r);
    lo = (short)((u2 + 0x7fffu + ((u2 >> 16) & 1u)) >> 16);
}

struct SJ {                       // one scan job (one layer, one time tile)
    const float* xg;              // [NB*TILE][512] gate' order, no bias
    const float* whh;             // [512][128] original gate order
    const float* bias;            // [512] original order
    const float* h0;              // [NB][128] initial h for this layer
    float* sth; float* stc;       // [NB][128] carried state
    _Float16* hout;               // layer0: [NB*TILE][128] f16 (else null)
    int first;                    // t0 == 0 ?
    int dofc;                     // fuse final FC (layer1 last tile)
};

// ---------------------------------------------------------------------------
// Dual-job recurrent scan, MFMA matvec. grid = nbA + nbB blocks, 512 thr.
// Per wave: gate' columns 64w..64w+63 as 4 MFMA N-tiles. A operand = h
// broadcast into all 16 M-rows (every D row = gate vector; M-waste is free
// on the MFMA pipe). W_hh fragments register/AGPR-resident (MFMA reads AGPRs
// natively -> no shuttle). Gate for lane l is acc[l>>4][0] -> 3 cndmask.
// Then DPP quad exchange + fp32 nonlinearity; h (f16) double-buffered in
// LDS; ONE barrier per step.
// ---------------------------------------------------------------------------
template<int TILE>
__global__ __launch_bounds__(512, 4)
void scan2(SJ ja, SJ jb, int nbA,
           const float* __restrict__ fcw, const float* __restrict__ fcb,
           float* __restrict__ out)
{
    __shared__ _Float16 __align__(16) lds_h[2][H];   // 512 B
    __shared__ float lds_r[H];

    const int bid = blockIdx.x;
    const bool isA = bid < nbA;
    const SJ J = isA ? ja : jb;
    const int b = isA ? bid : bid - nbA;

    const int t    = threadIdx.x;
    const int lane = t & 63;
    const int w    = t >> 6;
    const int kg   = t & 3;
    const int hu   = t >> 2;
    const int kt_grp = lane >> 4;        // k-subgroup 0..3 within frag

    // B fragments: wfrag[j][kt] = W_hh[gate' col n][k], n = 64w+16j+(lane&15),
    // k = 32*kt + kt_grp*8 + jj  (16x16x32 f16 B-operand layout, n = lane&15)
    f16x8 wfrag[4][4];
    #pragma unroll
    for (int j = 0; j < 4; ++j) {
        const int n  = 64 * w + 16 * j + (lane & 15);
        const int pn = (n & 3) * 128 + (n >> 2);     // original gate row
        const float* wr = J.whh + (size_t)pn * H;
        #pragma unroll
        for (int kt = 0; kt < 4; ++kt) {
            const int base = 32 * kt + kt_grp * 8;
            float4 v0 = *(const float4*)(wr + base);
            float4 v1 = *(const float4*)(wr + base + 4);
            wfrag[j][kt] = (f16x8){(_Float16)v0.x, (_Float16)v0.y, (_Float16)v0.z, (_Float16)v0.w,
                                   (_Float16)v1.x, (_Float16)v1.y, (_Float16)v1.z, (_Float16)v1.w};
        }
    }
    const float bj = J.bias[kg * 128 + hu];   // gate' t -> original row (t&3)*128+(t>>2)

    if (t < H) {
        float hv = J.first ? J.h0[(size_t)b * H + t] : J.sth[(size_t)b * H + t];
        lds_h[0][t] = (_Float16)hv;
    }
    float c = J.first ? 0.0f : J.stc[(size_t)b * H + hu];
    __syncthreads();

    const float* xgb = J.xg + (size_t)b * TILE * G4 + t;
    float xv0 = xgb[0];
    float xv1 = (TILE > 1) ? xgb[G4] : 0.0f;

    const bool s4 = (lane & 16) != 0;
    const bool s5 = (lane & 32) != 0;

    float hreg = 0.0f;
    int cur = 0;

    for (int tt = 0; tt < TILE; ++tt) {
        // A fragments: h broadcast over M; af[kt][jj] = h[32kt + kt_grp*8 + jj]
        const _Float16* hb = &lds_h[cur][0];
        f16x8 af0 = *(const f16x8*)(hb +  0 + kt_grp * 8);
        f16x8 af1 = *(const f16x8*)(hb + 32 + kt_grp * 8);
        f16x8 af2 = *(const f16x8*)(hb + 64 + kt_grp * 8);
        f16x8 af3 = *(const f16x8*)(hb + 96 + kt_grp * 8);

        const f32x4 z = (f32x4){0.f, 0.f, 0.f, 0.f};
        f32x4 a0 = __builtin_amdgcn_mfma_f32_16x16x32_f16(af0, wfrag[0][0], z, 0, 0, 0);
        f32x4 a1 = __builtin_amdgcn_mfma_f32_16x16x32_f16(af0, wfrag[1][0], z, 0, 0, 0);
        f32x4 a2 = __builtin_amdgcn_mfma_f32_16x16x32_f16(af0, wfrag[2][0], z, 0, 0, 0);
        f32x4 a3 = __builtin_amdgcn_mfma_f32_16x16x32_f16(af0, wfrag[3][0], z, 0, 0, 0);
        a0 = __builtin_amdgcn_mfma_f32_16x16x32_f16(af1, wfrag[0][1], a0, 0, 0, 0);
        a1 = __builtin_amdgcn_mfma_f32_16x16x32_f16(af1, wfrag[1][1], a1, 0, 0, 0);
        a2 = __builtin_amdgcn_mfma_f32_16x16x32_f16(af1, wfrag[2][1], a2, 0, 0, 0);
        a3 = __builtin_amdgcn_mfma_f32_16x16x32_f16(af1, wfrag[3][1], a3, 0, 0, 0);
        a0 = __builtin_amdgcn_mfma_f32_16x16x32_f16(af2, wfrag[0][2], a0, 0, 0, 0);
        a1 = __builtin_amdgcn_mfma_f32_16x16x32_f16(af2, wfrag[1][2], a1, 0, 0, 0);
        a2 = __builtin_amdgcn_mfma_f32_16x16x32_f16(af2, wfrag[2][2], a2, 0, 0, 0);
        a3 = __builtin_amdgcn_mfma_f32_16x16x32_f16(af2, wfrag[3][2], a3, 0, 0, 0);
        a0 = __builtin_amdgcn_mfma_f32_16x16x32_f16(af3, wfrag[0][3], a0, 0, 0, 0);
        a1 = __builtin_amdgcn_mfma_f32_16x16x32_f16(af3, wfrag[1][3], a1, 0, 0, 0);
        a2 = __builtin_amdgcn_mfma_f32_16x16x32_f16(af3, wfrag[2][3], a2, 0, 0, 0);
        a3 = __builtin_amdgcn_mfma_f32_16x16x32_f16(af3, wfrag[3][3], a3, 0, 0, 0);

        // gate' (64w + lane) = N-tile (lane>>4), col (lane&15); any acc row
        float glo = s4 ? a1[0] : a0[0];
        float ghi = s4 ? a3[0] : a2[0];
        float g   = (s5 ? ghi : glo) + xv0 + bj;

        xv0 = xv1;
        int tn = (tt + 2 < TILE) ? (tt + 2) : (TILE - 1);
        xv1 = xgb[(size_t)tn * G4];

        // quad exchange: all lanes get i,f,g,o of hu
        float gi = DPPQ(g, 0x00);
        float gf = DPPQ(g, 0x55);
        float gg = DPPQ(g, 0xAA);
        float go = DPPQ(g, 0xFF);

        c = sigf(gf) * c + sigf(gi) * tanhf_(gg);
        float h = sigf(go) * tanhf_(c);
        hreg = h;

        if (kg == 0) {
            lds_h[cur ^ 1][hu] = (_Float16)h;
            if (J.hout) J.hout[((size_t)b * TILE + tt) * H + hu] = (_Float16)h;
        }
        cur ^= 1;
        __syncthreads();
    }

    if (kg == 0) {
        J.sth[(size_t)b * H + hu] = hreg;
        J.stc[(size_t)b * H + hu] = c;
    }

    if (J.dofc) {
        if (kg == 0) lds_r[hu] = hreg * fcw[hu];
        __syncthreads();
        if (t == 0) {
            float s = fcb[0];
            for (int k = 0; k < H; ++k) s += lds_r[k];
            out[b] = s;
        }
    }
}

// ---------------------------------------------------------------------------
// MFMA GEMM: Out[r][n'] = sum_k A[r][k] * W[perm(n')][k]; bf16 3-term split.
// A may be fp32 or f16 (aHalf). Dual-job launch; tile 128x128, BK=64.
// ---------------------------------------------------------------------------
__global__ __launch_bounds__(256, 2)
void gemm_xg(const void* __restrict__ A0, const float* __restrict__ W0,
             float* __restrict__ O0, int K0, int As0, int t00, int aH0,
             const void* __restrict__ A1, const float* __restrict__ W1,
             float* __restrict__ O1, int K1, int As1, int t01, int aH1,
             int nbA, int lgT, int lgM)
{
    __shared__ short Ah[128][72], Al[128][72], Wh[128][72], Wl[128][72];

    const void* A; const float* W; float* O; int K, Astride, t0, aHalf;
    int bid = blockIdx.x;
    if (bid < nbA) { A = A0; W = W0; O = O0; K = K0; Astride = As0; t0 = t00; aHalf = aH0; }
    else { bid -= nbA; A = A1; W = W1; O = O1; K = K1; Astride = As1; t0 = t01; aHalf = aH1; }

    const int Mmask = (1 << lgM) - 1;
    const int m0 = (bid & Mmask) << 7;
    const int n0 = (bid >> lgM) << 7;
    const int Tmask = (1 << lgT) - 1;

    const int j = threadIdx.x;
    const int lane = j & 63, wv = j >> 6;
    const int wm = wv >> 1, wn = wv & 1;
    const int q = lane >> 4, n16 = lane & 15;

    f32x4 acc[4][4];
    #pragma unroll
    for (int a = 0; a < 4; ++a)
        #pragma unroll
        for (int bq = 0; bq < 4; ++bq) acc[a][bq] = (f32x4){0.f, 0.f, 0.f, 0.f};

    const int npass = K >> 6;
    for (int kp = 0; kp < npass; ++kp) {
        #pragma unroll
        for (int it = 0; it < 8; ++it) {
            int cidx = j + it * 256;
            int r = cidx >> 4, kc = (cidx & 15) << 2;
            int gr = m0 + r;
            size_t arow = (size_t)(gr >> lgT) * Astride + t0 + (gr & Tmask);
            float4 v;
            if (aHalf) {
                f16x4 hv4 = *(const f16x4*)((const _Float16*)A + arow * K + kp * 64 + kc);
                v = make_float4((float)hv4[0], (float)hv4[1], (float)hv4[2], (float)hv4[3]);
            } else {
                v = *(const float4*)((const float*)A + arow * K + kp * 64 + kc);
            }
            short h0s, l0s, h1s, l1s, h2s, l2s, h3s, l3s;
            split_bf16(v.x, h0s, l0s); split_bf16(v.y, h1s, l1s);
            split_bf16(v.z, h2s, l2s); split_bf16(v.w, h3s, l3s);
            *(short4*)&Ah[r][kc] = make_short4(h0s, h1s, h2s, h3s);
            *(short4*)&Al[r][kc] = make_short4(l0s, l1s, l2s, l3s);
        }
        #pragma unroll
        for (int it = 0; it < 8; ++it) {
            int cidx = j + it * 256;
            int r = cidx >> 4, kc = (cidx & 15) << 2;
            int n = n0 + r;
            int pn = (n & 3) * 128 + (n >> 2);
            float4 v = *(const float4*)(W + (size_t)pn * K + kp * 64 + kc);
            short h0s, l0s, h1s, l1s, h2s, l2s, h3s, l3s;
            split_bf16(v.x, h0s, l0s); split_bf16(v.y, h1s, l1s);
            split_bf16(v.z, h2s, l2s); split_bf16(v.w, h3s, l3s);
            *(short4*)&Wh[r][kc] = make_short4(h0s, h1s, h2s, h3s);
            *(short4*)&Wl[r][kc] = make_short4(l0s, l1s, l2s, l3s);
        }
        __syncthreads();

        #pragma unroll
        for (int kt = 0; kt < 2; ++kt) {
            const int kk = kt * 32 + q * 8;
            bf16x8 ah[4], al[4];
            #pragma unroll
            for (int mt = 0; mt < 4; ++mt) {
                int row = wm * 64 + mt * 16 + n16;
                ah[mt] = *(const bf16x8*)&Ah[row][kk];
                al[mt] = *(const bf16x8*)&Al[row][kk];
            }
            #pragma unroll
            for (int nt = 0; nt < 4; ++nt) {
                int col = wn * 64 + nt * 16 + n16;
                bf16x8 bh = *(const bf16x8*)&Wh[col][kk];
                bf16x8 bl = *(const bf16x8*)&Wl[col][kk];
                #pragma unroll
                for (int mt = 0; mt < 4; ++mt) {
                    acc[mt][nt] = __builtin_amdgcn_mfma_f32_16x16x32_bf16(ah[mt], bh, acc[mt][nt], 0, 0, 0);
                    acc[mt][nt] = __builtin_amdgcn_mfma_f32_16x16x32_bf16(al[mt], bh, acc[mt][nt], 0, 0, 0);
                    acc[mt][nt] = __builtin_amdgcn_mfma_f32_16x16x32_bf16(ah[mt], bl, acc[mt][nt], 0, 0, 0);
                }
            }
        }
        __syncthreads();
    }

    #pragma unroll
    for (int mt = 0; mt < 4; ++mt) {
        #pragma unroll
        for (int nt = 0; nt < 4; ++nt) {
            int row = m0 + wm * 64 + mt * 16 + q * 4;
            int col = n0 + wn * 64 + nt * 16 + n16;
            #pragma unroll
            for (int r = 0; r < 4; ++r)
                O[(size_t)(row + r) * G4 + col] = acc[mt][nt][r];
        }
    }
}

template<int TILE>
static void run_all(const float* x, const float* h0,
                    const float* wih0, const float* whh0, const float* b0,
                    const float* wih1, const float* whh1, const float* b1,
                    const float* fcw, const float* fcb, float* out,
                    void* d_ws, hipStream_t stream)
{
    const int n_t = T / TILE;
    const int lgT = __builtin_ctz(TILE);
    const int lgM = lgT + 1;
    const int nbJ = 8 * TILE;   // (NB*TILE/128) * (512/128)

    float*    xg0 = (float*)d_ws;
    float*    xg1 = xg0 + (size_t)NB * TILE * G4;
    _Float16* h0s = (_Float16*)(xg1 + (size_t)NB * TILE * G4);
    float*    st  = (float*)(h0s + (size_t)NB * TILE * H);
    float* st_h0 = st, *st_c0 = st + NB * H, *st_h1 = st + 2 * NB * H, *st_c1 = st + 3 * NB * H;

    SJ l0, l1;
    l0.whh = whh0; l0.bias = b0; l0.h0 = h0;               l0.sth = st_h0; l0.stc = st_c0;
    l0.xg = xg0;   l0.hout = h0s; l0.dofc = 0;
    l1.whh = whh1; l1.bias = b1; l1.h0 = h0 + (size_t)NB * H; l1.sth = st_h1; l1.stc = st_c1;
    l1.xg = xg1;   l1.hout = nullptr;

    // xg0(0)
    gemm_xg<<<nbJ, 256, 0, stream>>>(x, wih0, xg0, DIN, T, 0, 0,
                                     x, wih0, xg0, DIN, T, 0, 0, nbJ, lgT, lgM);
    // scan_l0 tile 0 (solo)
    l0.first = 1;
    scan2<TILE><<<NB, 512, 0, stream>>>(l0, l0, NB, fcw, fcb, out);

    for (int k = 0; k < n_t; ++k) {
        // gemm: xg1(k) from h0s (f16); plus xg0(k+1) from x if it exists
        if (k + 1 < n_t) {
            gemm_xg<<<2 * nbJ, 256, 0, stream>>>(
                h0s, wih1, xg1, H, TILE, 0, 1,
                x, wih0, xg0, DIN, T, (k + 1) * TILE, 0, nbJ, lgT, lgM);
            // combined: scan_l0(k+1) || scan_l1(k)
            l0.first = 0;
            l1.first = (k == 0);
            l1.dofc = 0;
            scan2<TILE><<<2 * NB, 512, 0, stream>>>(l0, l1, NB, fcw, fcb, out);
        } else {
            gemm_xg<<<nbJ, 256, 0, stream>>>(
                h0s, wih1, xg1, H, TILE, 0, 1,
                h0s, wih1, xg1, H, TILE, 0, 1, nbJ, lgT, lgM);
            // final scan_l1 (solo, fused FC)
            l1.first = (k == 0);
            l1.dofc = 1;
            scan2<TILE><<<NB, 512, 0, stream>>>(l1, l1, NB, fcw, fcb, out);
        }
    }
}

extern "C" void kernel_launch(void* const* d_in, const int* in_sizes, int n_in,
                              void* d_out, int out_size, void* d_ws, size_t ws_size,
                              hipStream_t stream)
{
    const float* x    = (const float*)d_in[0];
    const float* h0   = (const float*)d_in[1];
    const float* wih0 = (const float*)d_in[2];
    const float* whh0 = (const float*)d_in[3];
    const float* b0   = (const float*)d_in[4];
    const float* wih1 = (const float*)d_in[5];
    const float* whh1 = (const float*)d_in[6];
    const float* b1   = (const float*)d_in[7];
    const float* fcw  = (const float*)d_in[8];
    const float* fcb  = (const float*)d_in[9];
    float* out = (float*)d_out;

    int TILE = 256;
    while (TILE > 16) {
        size_t need = (size_t)NB * TILE * (2 * G4 * 4 + H * 2) + (size_t)4 * NB * H * 4;
        if (need <= ws_size) break;
        TILE >>= 1;
    }

    switch (TILE) {
        case 256: run_all<256>(x, h0, wih0, whh0, b0, wih1, whh1, b1, fcw, fcb, out, d_ws, stream); break;
        case 128: run_all<128>(x, h0, wih0, whh0, b0, wih1, whh1, b1, fcw, fcb, out, d_ws, stream); break;
        case  64: run_all< 64>(x, h0, wih0, whh0, b0, wih1, whh1, b1, fcw, fcb, out, d_ws, stream); break;
        default:  run_all< 32>(x, h0, wih0, whh0, b0, wih1, whh1, b1, fcw, fcb, out, d_ws, stream); break;
    }
}